// Round 8
// baseline (463.751 us; speedup 1.0000x reference)
//
#include <hip/hip_runtime.h>
#include <cstdint>
#include <cstddef>
#include <cmath>

#define D 128

typedef short bf16x8 __attribute__((ext_vector_type(8)));
typedef float f32x4 __attribute__((ext_vector_type(4)));

__device__ __forceinline__ ushort f2b(float f) {
  uint x = __float_as_uint(f);
  uint r = ((x >> 16) & 1u) + 0x7fffu;   // round-to-nearest-even
  return (ushort)((x + r) >> 16);
}
__device__ __forceinline__ float b2f(ushort u) {
  return __uint_as_float(((uint)u) << 16);
}

// ======================= CSR build (XCD-partitioned) =======================
__global__ __launch_bounds__(256) void k_degree_p(const int* __restrict__ dst, int E,
    int* __restrict__ deg, float scale, int CE) {
  int part = blockIdx.x & 7, chunk = blockIdx.x >> 3;
  long base = (long)chunk * CE;
  for (int i = threadIdx.x; i < CE; i += 256) {
    long e = base + i;
    if (e < E) {
      int d = dst[e];
      int p = (int)((float)d * scale); if (p > 7) p = 7;
      if (p == part) atomicAdd(&deg[d], 1);
    }
  }
}

__global__ __launch_bounds__(256) void k_fill_p(const int* __restrict__ src,
    const int* __restrict__ dst, int E, int* __restrict__ cursor,
    int* __restrict__ csrc, float scale, int CE) {
  int part = blockIdx.x & 7, chunk = blockIdx.x >> 3;
  long base = (long)chunk * CE;
  for (int i = threadIdx.x; i < CE; i += 256) {
    long e = base + i;
    if (e < E) {
      int d = dst[e];
      int p = (int)((float)d * scale); if (p > 7) p = 7;
      if (p == part) {
        int s = src[e];
        int pos = atomicAdd(&cursor[d], 1);
        csrc[pos] = s;
      }
    }
  }
}

#define SCAN_T 256
#define SCAN_E 4
#define SCAN_CHUNK (SCAN_T * SCAN_E)

__global__ void k_scan_partial(const int* __restrict__ deg, int n, int* __restrict__ part) {
  __shared__ int s[SCAN_T];
  int base = blockIdx.x * SCAN_CHUNK;
  int sum = 0;
  for (int i = 0; i < SCAN_E; ++i) {
    int idx = base + (int)threadIdx.x * SCAN_E + i;
    if (idx < n) sum += deg[idx];
  }
  s[threadIdx.x] = sum; __syncthreads();
  for (int ofs = SCAN_T / 2; ofs > 0; ofs >>= 1) {
    if ((int)threadIdx.x < ofs) s[threadIdx.x] += s[threadIdx.x + ofs];
    __syncthreads();
  }
  if (threadIdx.x == 0) part[blockIdx.x] = s[0];
}

__global__ void k_scan_part_ex(int* __restrict__ part, int nb) {
  __shared__ int s[1024];
  int v = ((int)threadIdx.x < nb) ? part[threadIdx.x] : 0;
  s[threadIdx.x] = v; __syncthreads();
  for (int ofs = 1; ofs < 1024; ofs <<= 1) {
    int t = ((int)threadIdx.x >= ofs) ? s[threadIdx.x - ofs] : 0;
    __syncthreads();
    s[threadIdx.x] += t;
    __syncthreads();
  }
  if ((int)threadIdx.x < nb) part[threadIdx.x] = s[threadIdx.x] - v;  // exclusive
}

__global__ void k_scan_final(const int* __restrict__ deg, int n, const int* __restrict__ part,
                             int* __restrict__ rowptr, int* __restrict__ cursor, int E) {
  __shared__ int s[SCAN_T];
  int base = blockIdx.x * SCAN_CHUNK;
  int v[SCAN_E]; int local = 0;
  for (int i = 0; i < SCAN_E; ++i) {
    int idx = base + (int)threadIdx.x * SCAN_E + i;
    v[i] = (idx < n) ? deg[idx] : 0;
    local += v[i];
  }
  s[threadIdx.x] = local; __syncthreads();
  for (int ofs = 1; ofs < SCAN_T; ofs <<= 1) {
    int t = ((int)threadIdx.x >= ofs) ? s[threadIdx.x - ofs] : 0;
    __syncthreads();
    s[threadIdx.x] += t;
    __syncthreads();
  }
  int run = part[blockIdx.x] + s[threadIdx.x] - local;  // exclusive prefix
  for (int i = 0; i < SCAN_E; ++i) {
    int idx = base + (int)threadIdx.x * SCAN_E + i;
    if (idx < n) { rowptr[idx] = run; cursor[idx] = run; }
    run += v[i];
  }
  if (blockIdx.x == 0 && threadIdx.x == 0) rowptr[n] = E;
}

// ======================= fp32 -> bf16 convert =======================
__global__ void k_conv_bf16(const float* __restrict__ in, ushort* __restrict__ out, int n8) {
  int i = blockIdx.x * 256 + threadIdx.x;
  if (i >= n8) return;
  float4 a = ((const float4*)in)[i * 2];
  float4 b = ((const float4*)in)[i * 2 + 1];
  ushort4 o0 = {f2b(a.x), f2b(a.y), f2b(a.z), f2b(a.w)};
  ushort4 o1 = {f2b(b.x), f2b(b.y), f2b(b.z), f2b(b.w)};
  ((ushort4*)out)[i * 2] = o0;
  ((ushort4*)out)[i * 2 + 1] = o1;
}

// ======================= pack ALL weights to B-fragment order ==================
__global__ void k_pack_all(
    const float* __restrict__ Ws0, const float* __restrict__ Wn0,
    const float* __restrict__ Ws1, const float* __restrict__ Wn1,
    const float* __restrict__ Ws2, const float* __restrict__ Wn2,
    const float* __restrict__ Wp0, const float* __restrict__ Wp1,
    ushort* __restrict__ BpL0, ushort* __restrict__ BpL1, ushort* __restrict__ BpL2,
    ushort* __restrict__ BpP0, ushort* __restrict__ BpP1) {
  int o = blockIdx.x * 256 + threadIdx.x;   // total 131072
  const float *W0, *W1; ushort* out; int rel;
  if (o < 32768)       { W0 = Ws0; W1 = Wn0; out = BpL0; rel = o; }
  else if (o < 65536)  { W0 = Ws1; W1 = Wn1; out = BpL1; rel = o - 32768; }
  else if (o < 98304)  { W0 = Ws2; W1 = Wn2; out = BpL2; rel = o - 65536; }
  else if (o < 114688) { W0 = Wp0; W1 = Wp0; out = BpP0; rel = o - 98304; }
  else                 { W0 = Wp1; W1 = Wp1; out = BpP1; rel = o - 114688; }
  int j = rel & 7, lane = (rel >> 3) & 63, t = (rel >> 9) & 7, ks = rel >> 12;
  int k = ks * 32 + ((lane >> 4) * 8) + j;
  int n = t * 16 + (lane & 15);
  const float* W = (k < 128) ? W0 : W1;
  int kk = (k < 128) ? k : k - 128;
  out[rel] = f2b(W[(size_t)kk * D + n]);
}

// ======================= standalone mean aggregation ================
// 1 node per 16-lane group (4 nodes/wave) -> 25k waves: residency is
// HW-capped, not grid-capped. Index-prefetch (one round trip for the
// first 16 edge indices) + shfl-addressed pipelined row loop (2 rows in
// flight per group, 8 per wave). No LDS, low VGPR.
__global__ __launch_bounds__(256) void k_aggregate2(const ushort* __restrict__ h,
    const int* __restrict__ rowptr, const int* __restrict__ csrc,
    ushort* __restrict__ hn, int N) {
  int tid = threadIdx.x, lane = tid & 63;
  int wid = (int)((blockIdx.x * 256 + tid) >> 6);
  int g = lane >> 4, sub = lane & 15, gb = g << 4;
  int node = wid * 4 + g;
  if (node >= N) return;
  int beg = rowptr[node], end = rowptr[node + 1];
  int dg = end - beg;
  int dd = dg < 16 ? dg : 16;
  int i0 = beg + sub;
  int idxv = (i0 < end) ? csrc[i0] : 0;
  const ushort* hb = h + sub * 8;
  float f[8] = {0.f, 0.f, 0.f, 0.f, 0.f, 0.f, 0.f, 0.f};
  for (int e = 0; e < dd; e += 2) {
    int s0 = __shfl(idxv, gb + e);
    int s1 = __shfl(idxv, gb + e + 1);
    bf16x8 r0 = *(const bf16x8*)(hb + (size_t)s0 * D);
    if (e + 1 < dd) {
      bf16x8 r1 = *(const bf16x8*)(hb + (size_t)s1 * D);
      #pragma unroll
      for (int q = 0; q < 8; ++q)
        f[q] += b2f((ushort)r0[q]) + b2f((ushort)r1[q]);
    } else {
      #pragma unroll
      for (int q = 0; q < 8; ++q) f[q] += b2f((ushort)r0[q]);
    }
  }
  // rare deg>16 tail
  for (int i = beg + 16; i < end; ++i) {
    int s = csrc[i];
    bf16x8 v = *(const bf16x8*)(hb + (size_t)s * D);
    #pragma unroll
    for (int q = 0; q < 8; ++q) f[q] += b2f((ushort)v[q]);
  }
  float inv = (dg > 0) ? (1.0f / (float)dg) : 0.0f;
  bf16x8 o;
  #pragma unroll
  for (int q = 0; q < 8; ++q) o[q] = (short)f2b(f[q] * inv);
  *(bf16x8*)(hn + (size_t)node * D + sub * 8) = o;
}

// ======================= SAGE layer GEMM (MFMA, no LDS) =======================
// out[r][c] = act( sum_k A[r][k] Ws[k][c] + An[r][k] Wn[k][c] + b[c] )
__global__ __launch_bounds__(256) void k_gemm_mfma(
    const ushort* __restrict__ A, const ushort* __restrict__ An,
    const ushort* __restrict__ Bp, const float* __restrict__ bias,
    ushort* __restrict__ out, int N, int do_relu) {
  int tid = threadIdx.x;
  int wave = tid >> 6, lane = tid & 63;
  int m = lane & 15, kg = lane >> 4;
  int row0 = blockIdx.x * 64 + wave * 16;
  int ar = row0 + m; if (ar >= N) ar = N - 1;   // clamp reads; stores guarded
  const ushort* a_self = A  + (size_t)ar * D + kg * 8;
  const ushort* a_nei  = An + (size_t)ar * D + kg * 8;
  f32x4 acc[8];
  #pragma unroll
  for (int t = 0; t < 8; ++t) acc[t] = f32x4{0.f, 0.f, 0.f, 0.f};
  #pragma unroll
  for (int ks = 0; ks < 8; ++ks) {
    const ushort* ap = (ks < 4) ? a_self : a_nei;
    bf16x8 af = *(const bf16x8*)(ap + (ks & 3) * 32);
    const ushort* bb = Bp + (size_t)ks * 4096 + lane * 8;
    #pragma unroll
    for (int t = 0; t < 8; ++t)
      acc[t] = __builtin_amdgcn_mfma_f32_16x16x32_bf16(af, *(const bf16x8*)(bb + t * 512), acc[t], 0, 0, 0);
  }
  #pragma unroll
  for (int t = 0; t < 8; ++t) {
    int c = t * 16 + m;
    float bv = bias[c];
    #pragma unroll
    for (int i = 0; i < 4; ++i) {
      int r = row0 + kg * 4 + i;
      float v = acc[t][i] + bv;
      if (do_relu) v = fmaxf(v, 0.f);
      if (r < N) out[(size_t)r * D + c] = f2b(v);
    }
  }
}

// ======================= fused predictor MLP (MFMA, pos+neg merged) ============
__global__ __launch_bounds__(256) void k_predict_mfma(
    const ushort* __restrict__ h,
    const int* __restrict__ ps, const int* __restrict__ pd,
    const int* __restrict__ ns, const int* __restrict__ nd,
    const ushort* __restrict__ Bp0, const float* __restrict__ bp0,
    const ushort* __restrict__ Bp1, const float* __restrict__ bp1,
    const float* __restrict__ Wp2, const float* __restrict__ bp2,
    float* __restrict__ outp, int P, int pb) {
  __shared__ __align__(16) ushort z1p[4][2048];  // per-wave A-frag-packed z1
  int bi = blockIdx.x;
  const int* sidx; const int* didx; float* op;
  if (bi >= pb) { sidx = ns; didx = nd; op = outp + P; bi -= pb; }
  else          { sidx = ps; didx = pd; op = outp; }
  int tid = threadIdx.x;
  int wave = tid >> 6, lane = tid & 63;
  int m = lane & 15, kg = lane >> 4;
  int pair0 = bi * 64 + wave * 16;
  int prow = pair0 + m; int pr = (prow < P) ? prow : P - 1;
  int si = sidx[pr], di = didx[pr];
  const ushort* hs = h + (size_t)si * D + kg * 8;
  const ushort* hd = h + (size_t)di * D + kg * 8;
  f32x4 acc[8];
  #pragma unroll
  for (int t = 0; t < 8; ++t) acc[t] = f32x4{0.f, 0.f, 0.f, 0.f};
  // ---- GEMM1: z = hs*hd ; acc = z @ Wp0 ----
  #pragma unroll
  for (int ks = 0; ks < 4; ++ks) {
    bf16x8 as8 = *(const bf16x8*)(hs + ks * 32);
    bf16x8 ad8 = *(const bf16x8*)(hd + ks * 32);
    bf16x8 af;
    #pragma unroll
    for (int j = 0; j < 8; ++j) {
      float p = b2f((ushort)as8[j]) * b2f((ushort)ad8[j]);
      af[j] = (short)f2b(p);
    }
    const ushort* bb = Bp0 + (size_t)ks * 4096 + lane * 8;
    #pragma unroll
    for (int t = 0; t < 8; ++t)
      acc[t] = __builtin_amdgcn_mfma_f32_16x16x32_bf16(af, *(const bf16x8*)(bb + t * 512), acc[t], 0, 0, 0);
  }
  // ---- epilogue1: relu(acc + bp0) -> LDS in GEMM2 A-fragment packed order ----
  ushort* zp = &z1p[wave][0];
  #pragma unroll
  for (int t = 0; t < 8; ++t) {
    int c = t * 16 + m;
    float bv = bp0[c];
    int ks2 = c >> 5, kg2 = (c >> 3) & 3, j2 = c & 7;
    #pragma unroll
    for (int i = 0; i < 4; ++i) {
      float v = fmaxf(acc[t][i] + bv, 0.f);
      int l2 = kg2 * 16 + kg * 4 + i;     // consumer lane
      zp[(ks2 * 64 + l2) * 8 + j2] = f2b(v);
    }
  }
  __syncthreads();
  // ---- GEMM2: acc = z1 @ Wp1 ----
  #pragma unroll
  for (int t = 0; t < 8; ++t) acc[t] = f32x4{0.f, 0.f, 0.f, 0.f};
  #pragma unroll
  for (int ks = 0; ks < 4; ++ks) {
    bf16x8 af = *(const bf16x8*)(zp + (ks * 64 + lane) * 8);
    const ushort* bb = Bp1 + (size_t)ks * 4096 + lane * 8;
    #pragma unroll
    for (int t = 0; t < 8; ++t)
      acc[t] = __builtin_amdgcn_mfma_f32_16x16x32_bf16(af, *(const bf16x8*)(bb + t * 512), acc[t], 0, 0, 0);
  }
  // ---- final: z2 = relu(acc + bp1); logits = z2 @ Wp2 + bp2; sigmoid ----
  float p0[4] = {0.f, 0.f, 0.f, 0.f}, p1[4] = {0.f, 0.f, 0.f, 0.f};
  #pragma unroll
  for (int t = 0; t < 8; ++t) {
    int c = t * 16 + m;
    float bv = bp1[c];
    float wa = Wp2[(size_t)c * 2], wb = Wp2[(size_t)c * 2 + 1];
    #pragma unroll
    for (int i = 0; i < 4; ++i) {
      float z = fmaxf(acc[t][i] + bv, 0.f);
      p0[i] += z * wa;
      p1[i] += z * wb;
    }
  }
  #pragma unroll
  for (int msk = 1; msk <= 8; msk <<= 1) {
    #pragma unroll
    for (int i = 0; i < 4; ++i) {
      p0[i] += __shfl_xor(p0[i], msk);
      p1[i] += __shfl_xor(p1[i], msk);
    }
  }
  if (m == 0) {
    float c0 = bp2[0], c1 = bp2[1];
    #pragma unroll
    for (int i = 0; i < 4; ++i) {
      int r = pair0 + kg * 4 + i;
      if (r < P) {
        float l0 = p0[i] + c0, l1 = p1[i] + c1;
        op[r] = 1.0f / (1.0f + expf(l0 - l1));
      }
    }
  }
}

// ======================= launch =======================
extern "C" void kernel_launch(void* const* d_in, const int* in_sizes, int n_in,
                              void* d_out, int out_size, void* d_ws, size_t ws_size,
                              hipStream_t stream) {
  const float* x       = (const float*)d_in[0];
  const int*   src     = (const int*)d_in[1];
  const int*   dst     = (const int*)d_in[2];
  const int*   pos_src = (const int*)d_in[3];
  const int*   pos_dst = (const int*)d_in[4];
  const int*   neg_src = (const int*)d_in[5];
  const int*   neg_dst = (const int*)d_in[6];
  const float* Ws0 = (const float*)d_in[7],  *Wn0 = (const float*)d_in[8],  *b0 = (const float*)d_in[9];
  const float* Ws1 = (const float*)d_in[10], *Wn1 = (const float*)d_in[11], *b1 = (const float*)d_in[12];
  const float* Ws2 = (const float*)d_in[13], *Wn2 = (const float*)d_in[14], *b2 = (const float*)d_in[15];
  const float* Wp0 = (const float*)d_in[16], *bp0 = (const float*)d_in[17];
  const float* Wp1 = (const float*)d_in[18], *bp1 = (const float*)d_in[19];
  const float* Wp2 = (const float*)d_in[20], *bp2 = (const float*)d_in[21];
  const int N = in_sizes[0] / D;
  const int E = in_sizes[1];
  const int P = in_sizes[3];
  float* outp = (float*)d_out;

  char* ws = (char*)d_ws;
  size_t off = 0;
  auto alloc = [&](size_t bytes) -> void* {
    void* p = ws + off;
    off += (bytes + 255) & ~(size_t)255;
    return p;
  };
  ushort* xb    = (ushort*)alloc((size_t)N * D * 2);
  ushort* h1    = (ushort*)alloc((size_t)N * D * 2);
  ushort* h2    = (ushort*)alloc((size_t)N * D * 2);
  ushort* hn    = (ushort*)alloc((size_t)N * D * 2);
  ushort* BpL0  = (ushort*)alloc(256 * D * 2);
  ushort* BpL1  = (ushort*)alloc(256 * D * 2);
  ushort* BpL2  = (ushort*)alloc(256 * D * 2);
  ushort* BpP0  = (ushort*)alloc(128 * D * 2);
  ushort* BpP1  = (ushort*)alloc(128 * D * 2);
  int*    deg    = (int*)alloc((size_t)N * 4);
  int*    rowptr = (int*)alloc((size_t)(N + 1) * 4);
  int*    cursor = (int*)alloc((size_t)N * 4);
  int*    part   = (int*)alloc(4096);
  int*    csrc   = (int*)alloc((size_t)E * 4);
  (void)ws_size; (void)n_in; (void)out_size;

  const float pscale = 8.0f / (float)N;
  const int CB = 96;                           // blocks per part
  const int CE = (E + CB - 1) / CB;            // edges per chunk

  // --- CSR build (XCD-partitioned) ---
  hipMemsetAsync(deg, 0, (size_t)N * 4, stream);
  k_degree_p<<<8 * CB, 256, 0, stream>>>(dst, E, deg, pscale, CE);
  int nb = (N + SCAN_CHUNK - 1) / SCAN_CHUNK;
  k_scan_partial<<<nb, SCAN_T, 0, stream>>>(deg, N, part);
  k_scan_part_ex<<<1, 1024, 0, stream>>>(part, nb);
  k_scan_final<<<nb, SCAN_T, 0, stream>>>(deg, N, part, rowptr, cursor, E);
  k_fill_p<<<8 * CB, 256, 0, stream>>>(src, dst, E, cursor, csrc, pscale, CE);

  // --- conversions / weight packing ---
  int n8 = N * D / 8;
  k_conv_bf16<<<(n8 + 255) / 256, 256, 0, stream>>>(x, xb, n8);
  k_pack_all<<<512, 256, 0, stream>>>(Ws0, Wn0, Ws1, Wn1, Ws2, Wn2, Wp0, Wp1,
                                      BpL0, BpL1, BpL2, BpP0, BpP1);

  int aggb = (N + 15) / 16;      // 4 nodes/wave, 4 waves/block
  int gemb = (N + 63) / 64;
  k_aggregate2<<<aggb, 256, 0, stream>>>(xb, rowptr, csrc, hn, N);
  k_gemm_mfma<<<gemb, 256, 0, stream>>>(xb, hn, BpL0, b0, h1, N, 1);
  k_aggregate2<<<aggb, 256, 0, stream>>>(h1, rowptr, csrc, hn, N);
  k_gemm_mfma<<<gemb, 256, 0, stream>>>(h1, hn, BpL1, b1, h2, N, 1);
  k_aggregate2<<<aggb, 256, 0, stream>>>(h2, rowptr, csrc, hn, N);
  k_gemm_mfma<<<gemb, 256, 0, stream>>>(h2, hn, BpL2, b2, xb, N, 0);

  int pb = (P + 63) / 64;
  k_predict_mfma<<<2 * pb, 256, 0, stream>>>(xb, pos_src, pos_dst, neg_src, neg_dst,
                                             BpP0, bp0, BpP1, bp1, Wp2, bp2, outp, P, pb);
}